// Round 5
// baseline (78.318 us; speedup 1.0000x reference)
//
#include <hip/hip_runtime.h>
#include <math.h>

#define BB 32
#define SS 2048
#define DD 1024
#define CHUNKS 32                        // chunks per batch (k_main grid.x)
#define ROWS_PER_CHUNK (SS / CHUNKS)     // 64
#define NWAVES 4
#define ROWS_PER_WAVE (ROWS_PER_CHUNK / NWAVES)  // 16
#define PSTRIDE (DD + 4)                 // partial stride (16B aligned)

// k_v split
#define ESPL 8
#define EPB (DD / ESPL)                  // 128 e per block
#define VBG 8                            // b-group blocks
#define VBPG (BB / VBG)                  // 4 b per block

// k_tail split
#define ECH 8
#define EPB_OUT (DD / ECH)               // 128 e per block

typedef float f32x4 __attribute__((ext_vector_type(4)));

__device__ __forceinline__ f32x4 ldnt4(const float* p) {
    return __builtin_nontemporal_load(reinterpret_cast<const f32x4*>(p));
}
__device__ __forceinline__ f32x4 ld4(const float* p) {
    return *reinterpret_cast<const f32x4*>(p);
}

// ---------------- K1: part_v[es][b][d] = sum_{e in es-range} st[b,e]*W[e,d] ----------------
// MLP fix: 8 independent W loads in flight per iteration group.
__global__ __launch_bounds__(256) void k_v(const float* __restrict__ st,
                                           const float* __restrict__ W,
                                           float* __restrict__ part_v) {
    const int dchunk = blockIdx.x;       // 0..3
    const int es = blockIdx.y;           // 0..7
    const int bg = blockIdx.z;           // 0..7
    const int tid = threadIdx.x;
    const int d = dchunk * 256 + tid;
    const int e0 = es * EPB;
    const int b0 = bg * VBPG;

    __shared__ float st_s[VBPG][EPB];    // 2 KB
    for (int i = tid; i < VBPG * EPB; i += 256)
        st_s[i >> 7][i & 127] = st[(b0 + (i >> 7)) * DD + e0 + (i & 127)];
    __syncthreads();

    float acc[VBPG];
#pragma unroll
    for (int j = 0; j < VBPG; ++j) acc[j] = 0.f;

    const float* Wd = W + d;
    for (int e = 0; e < EPB; e += 8) {
        float w[8];
#pragma unroll
        for (int q = 0; q < 8; ++q)
            w[q] = Wd[(size_t)(e0 + e + q) * DD];
#pragma unroll
        for (int q = 0; q < 8; ++q)
#pragma unroll
            for (int j = 0; j < VBPG; ++j) acc[j] += st_s[j][e + q] * w[q];
    }
#pragma unroll
    for (int j = 0; j < VBPG; ++j)
        part_v[((size_t)es * BB + b0 + j) * DD + d] = acc[j];
}

// ---------------- K2: main single pass over hx (online softmax, 2-row groups, dbuf) ----------------
__global__ __launch_bounds__(256, 4) void k_main(const float* __restrict__ hx,
                                                 const float* __restrict__ mask,
                                                 const float* __restrict__ part_v,
                                                 const float* __restrict__ st,
                                                 const float* __restrict__ bias,
                                                 float* __restrict__ part) {
    const int chunk = blockIdx.x;
    const int b = blockIdx.y;
    const int tid = threadIdx.x;
    const int wave = tid >> 6;
    const int lane = tid & 63;

    // v fragment (lane l owns cols 256k+4l..+3), reduced over the 8 e-splits
    f32x4 vr[4];
#pragma unroll
    for (int k = 0; k < 4; ++k) vr[k] = (f32x4)(0.f);
#pragma unroll
    for (int es = 0; es < ESPL; ++es) {
        const float* pv = part_v + ((size_t)es * BB + b) * DD + 4 * lane;
#pragma unroll
        for (int k = 0; k < 4; ++k) vr[k] += ld4(pv + k * 256);
    }

    // cb = dot(bias, st[b]) computed redundantly per wave (L2-hot reads)
    float cb = 0.f;
    {
        const float* stb = st + b * DD + 4 * lane;
        const float* bb = bias + 4 * lane;
#pragma unroll
        for (int k = 0; k < 4; ++k) {
            f32x4 bv = ld4(bb + k * 256);
            f32x4 sv = ld4(stb + k * 256);
            cb += bv.x * sv.x + bv.y * sv.y + bv.z * sv.z + bv.w * sv.w;
        }
#pragma unroll
        for (int o = 32; o; o >>= 1) cb += __shfl_xor(cb, o, 64);
    }

    const int s0 = chunk * ROWS_PER_CHUNK + wave * ROWS_PER_WAVE;
    const float* hxb = hx + (size_t)b * SS * DD + 4 * lane;
    const float* mb = mask + (size_t)b * SS;

    float m = -INFINITY, l = 0.f;
    f32x4 u[4];
#pragma unroll
    for (int k = 0; k < 4; ++k) u[k] = (f32x4)(0.f);

    f32x4 hA[2][4], hB[2][4];

    auto loadrows = [&](f32x4 (&h)[2][4], int s) {
        const float* r0 = hxb + (size_t)s * DD;
#pragma unroll
        for (int k = 0; k < 4; ++k) {
            h[0][k] = ldnt4(r0 + k * 256);
            h[1][k] = ldnt4(r0 + DD + k * 256);
        }
    };

    auto compute = [&](const f32x4 (&h)[2][4], int s) {
        float d0 = 0.f, d1 = 0.f;
#pragma unroll
        for (int k = 0; k < 4; ++k) {
            d0 += h[0][k].x * vr[k].x + h[0][k].y * vr[k].y + h[0][k].z * vr[k].z + h[0][k].w * vr[k].w;
            d1 += h[1][k].x * vr[k].x + h[1][k].y * vr[k].y + h[1][k].z * vr[k].z + h[1][k].w * vr[k].w;
        }
        // select-mix reduce: 1 mix + 5 butterfly + 1 gather = 7 shfls for 2 rows
        const bool odd = (lane & 1);
        float a = odd ? d1 : d0;
        float t = odd ? d0 : d1;
        a += __shfl_xor(t, 1, 64);
        a += __shfl_xor(a, 2, 64);
        a += __shfl_xor(a, 4, 64);
        a += __shfl_xor(a, 8, 64);
        a += __shfl_xor(a, 16, 64);
        a += __shfl_xor(a, 32, 64);
        const float o = __shfl_xor(a, 1, 64);
        const float dd0 = odd ? o : a;
        const float dd1 = odd ? a : o;

        const float2 mk = *reinterpret_cast<const float2*>(mb + s);
        const float sc0 = (dd0 + cb) * (mk.x + (1.0f - mk.x) * 1e-18f);
        const float sc1 = (dd1 + cb) * (mk.y + (1.0f - mk.y) * 1e-18f);

        const float gm = fmaxf(sc0, sc1);
        if (gm > m) {                        // wave-uniform (post-reduce values)
            const float f = __expf(m - gm);  // 0 on first group (m = -inf)
            l *= f;
#pragma unroll
            for (int k = 0; k < 4; ++k) u[k] *= f;
            m = gm;
        }
        const float p0 = __expf(sc0 - m);
        const float p1 = __expf(sc1 - m);
        l += p0 + p1;
#pragma unroll
        for (int k = 0; k < 4; ++k) u[k] += p0 * h[0][k] + p1 * h[1][k];
    };

    // software pipeline over 8 groups of 2 rows, static A/B alternation
    loadrows(hA, s0);
#pragma unroll
    for (int g = 0; g < ROWS_PER_WAVE / 2 - 1; ++g) {
        if (g & 1) { loadrows(hA, s0 + 2 * (g + 1)); compute(hB, s0 + 2 * g); }
        else       { loadrows(hB, s0 + 2 * (g + 1)); compute(hA, s0 + 2 * g); }
    }
    compute(hB, s0 + ROWS_PER_WAVE - 2);   // last group (loaded at g=6 into hB)

    // combine 4 waves in LDS
    __shared__ float s_m[NWAVES], s_l[NWAVES];
    __shared__ float s_u[NWAVES][DD];   // 16 KB
    if (lane == 0) { s_m[wave] = m; s_l[wave] = l; }
#pragma unroll
    for (int k = 0; k < 4; ++k)
        *reinterpret_cast<f32x4*>(&s_u[wave][k * 256 + 4 * lane]) = u[k];
    __syncthreads();

    const float M = fmaxf(fmaxf(s_m[0], s_m[1]), fmaxf(s_m[2], s_m[3]));
    const float f0 = __expf(s_m[0] - M), f1 = __expf(s_m[1] - M);
    const float f2 = __expf(s_m[2] - M), f3 = __expf(s_m[3] - M);
    const float L = s_l[0] * f0 + s_l[1] * f1 + s_l[2] * f2 + s_l[3] * f3;

    float* pb = part + (size_t)(b * CHUNKS + chunk) * PSTRIDE;
    f32x4 a0 = ld4(&s_u[0][4 * tid]);
    f32x4 a1 = ld4(&s_u[1][4 * tid]);
    f32x4 a2 = ld4(&s_u[2][4 * tid]);
    f32x4 a3 = ld4(&s_u[3][4 * tid]);
    f32x4 acc = a0 * f0 + a1 * f1 + a2 * f2 + a3 * f3;
    *reinterpret_cast<f32x4*>(pb + 4 * tid) = acc;
    if (tid == 0) { pb[DD] = M; pb[DD + 1] = L; }
}

// ---------------- K3 (fused reduce+out): per block = one batch b, 128 e values ----------------
__global__ __launch_bounds__(256) void k_tail(const float* __restrict__ part,
                                              const float* __restrict__ W,
                                              const float* __restrict__ bias,
                                              float* __restrict__ out) {
    const int ec = blockIdx.x;           // 0..7
    const int b = blockIdx.y;            // 0..31
    const int tid = threadIdx.x;
    const int wave = tid >> 6;
    const int lane = tid & 63;
    const float* pb = part + (size_t)b * CHUNKS * PSTRIDE;

    __shared__ float s_f[CHUNKS];
    __shared__ float ubar_s[DD];         // 4 KB

    // every wave redundantly computes M, L (cheap, L2-hot)
    const float mi = (lane < CHUNKS) ? pb[lane * PSTRIDE + DD] : -INFINITY;
    float M = mi;
#pragma unroll
    for (int o = 32; o; o >>= 1) M = fmaxf(M, __shfl_xor(M, o, 64));
    const float li = (lane < CHUNKS) ? pb[lane * PSTRIDE + DD + 1] : 0.f;
    const float fi = (lane < CHUNKS) ? __expf(mi - M) : 0.f;
    float L = li * fi;
#pragma unroll
    for (int o = 32; o; o >>= 1) L += __shfl_xor(L, o, 64);
    if (wave == 0 && lane < CHUNKS) s_f[lane] = fi;
    __syncthreads();
    const float invL = 1.f / L;

    // phase A: ubar[4*tid..+3] = invL * sum_i f_i * part[i][4*tid..+3]
    f32x4 acc = (f32x4)(0.f);
#pragma unroll
    for (int i = 0; i < CHUNKS; ++i)
        acc += s_f[i] * ld4(pb + (size_t)i * PSTRIDE + 4 * tid);
    acc *= invL;
    *reinterpret_cast<f32x4*>(&ubar_s[4 * tid]) = acc;
    __syncthreads();

    // phase B: 128 e per block, 32 per wave, 4 at a time
    f32x4 ur[4];
#pragma unroll
    for (int k = 0; k < 4; ++k) ur[k] = ld4(&ubar_s[k * 256 + 4 * lane]);

    const int ebase = ec * EPB_OUT + wave * (EPB_OUT / NWAVES);  // 32 e per wave
    for (int i = 0; i < 8; ++i) {
        const int e = ebase + 4 * i;
        f32x4 w0[4], w1[4], w2[4], w3[4];
        const float* wr = W + (size_t)e * DD + 4 * lane;
#pragma unroll
        for (int k = 0; k < 4; ++k) {
            w0[k] = ld4(wr + k * 256);
            w1[k] = ld4(wr + DD + k * 256);
            w2[k] = ld4(wr + 2 * DD + k * 256);
            w3[k] = ld4(wr + 3 * DD + k * 256);
        }
        float d0 = 0.f, d1 = 0.f, d2 = 0.f, d3 = 0.f;
#pragma unroll
        for (int k = 0; k < 4; ++k) {
            d0 += w0[k].x * ur[k].x + w0[k].y * ur[k].y + w0[k].z * ur[k].z + w0[k].w * ur[k].w;
            d1 += w1[k].x * ur[k].x + w1[k].y * ur[k].y + w1[k].z * ur[k].z + w1[k].w * ur[k].w;
            d2 += w2[k].x * ur[k].x + w2[k].y * ur[k].y + w2[k].z * ur[k].z + w2[k].w * ur[k].w;
            d3 += w3[k].x * ur[k].x + w3[k].y * ur[k].y + w3[k].z * ur[k].z + w3[k].w * ur[k].w;
        }
#pragma unroll
        for (int o = 32; o; o >>= 1) {
            d0 += __shfl_xor(d0, o, 64);
            d1 += __shfl_xor(d1, o, 64);
            d2 += __shfl_xor(d2, o, 64);
            d3 += __shfl_xor(d3, o, 64);
        }
        if (lane == 0) {
            out[(size_t)b * DD + e + 0] = d0 + bias[e + 0];
            out[(size_t)b * DD + e + 1] = d1 + bias[e + 1];
            out[(size_t)b * DD + e + 2] = d2 + bias[e + 2];
            out[(size_t)b * DD + e + 3] = d3 + bias[e + 3];
        }
    }
}

extern "C" void kernel_launch(void* const* d_in, const int* in_sizes, int n_in,
                              void* d_out, int out_size, void* d_ws, size_t ws_size,
                              hipStream_t stream) {
    const float* st   = (const float*)d_in[0];   // [B,D]
    const float* hx   = (const float*)d_in[1];   // [B,S,D]
    const float* msk  = (const float*)d_in[2];   // [B,S]
    const float* W    = (const float*)d_in[3];   // [D,D]
    const float* bias = (const float*)d_in[4];   // [D]
    float* out = (float*)d_out;                  // [B,D]

    float* ws = (float*)d_ws;
    float* part_v = ws;                                   // ESPL*B*D = 256K floats
    float* part   = part_v + (size_t)ESPL * BB * DD;      // B*CHUNKS*PSTRIDE

    k_v<<<dim3(4, ESPL, VBG), 256, 0, stream>>>(st, W, part_v);
    k_main<<<dim3(CHUNKS, BB), 256, 0, stream>>>(hx, msk, part_v, st, bias, part);
    k_tail<<<dim3(ECH, BB), 256, 0, stream>>>(part, W, bias, out);
}

// Round 6
// 69.822 us; speedup vs baseline: 1.1217x; 1.1217x over previous
//
#include <hip/hip_runtime.h>
#include <math.h>

#define BB 32
#define SS 2048
#define DD 1024
#define CHUNKS 32                        // chunks per batch (k_main grid.x)
#define ROWS_PER_CHUNK (SS / CHUNKS)     // 64
#define NWAVES 4
#define ROWS_PER_WAVE (ROWS_PER_CHUNK / NWAVES)  // 16
#define PSTRIDE (DD + 4)                 // partial stride (16B aligned)

// k_v split
#define ESPL 8
#define EPB (DD / ESPL)                  // 128 e per block
#define VBG 8                            // b-group blocks
#define VBPG (BB / VBG)                  // 4 b per block

// k_reduce split
#define DSPL 4                           // 256 cols per block

typedef float f32x4 __attribute__((ext_vector_type(4)));

__device__ __forceinline__ f32x4 ldnt4(const float* p) {
    return __builtin_nontemporal_load(reinterpret_cast<const f32x4*>(p));
}
__device__ __forceinline__ f32x4 ld4(const float* p) {
    return *reinterpret_cast<const f32x4*>(p);
}

// ---------------- K1: part_v[es][b][d] = sum_{e in es-range} st[b,e]*W[e,d] ----------------
__global__ __launch_bounds__(256) void k_v(const float* __restrict__ st,
                                           const float* __restrict__ W,
                                           float* __restrict__ part_v) {
    const int dchunk = blockIdx.x;       // 0..3
    const int es = blockIdx.y;           // 0..7
    const int bg = blockIdx.z;           // 0..7
    const int tid = threadIdx.x;
    const int d = dchunk * 256 + tid;
    const int e0 = es * EPB;
    const int b0 = bg * VBPG;

    __shared__ float st_s[VBPG][EPB];    // 2 KB
    for (int i = tid; i < VBPG * EPB; i += 256)
        st_s[i >> 7][i & 127] = st[(b0 + (i >> 7)) * DD + e0 + (i & 127)];
    __syncthreads();

    float acc[VBPG];
#pragma unroll
    for (int j = 0; j < VBPG; ++j) acc[j] = 0.f;

    const float* Wd = W + d;
    for (int e = 0; e < EPB; e += 8) {
        float w[8];
#pragma unroll
        for (int q = 0; q < 8; ++q)
            w[q] = Wd[(size_t)(e0 + e + q) * DD];
#pragma unroll
        for (int q = 0; q < 8; ++q)
#pragma unroll
            for (int j = 0; j < VBPG; ++j) acc[j] += st_s[j][e + q] * w[q];
    }
#pragma unroll
    for (int j = 0; j < VBPG; ++j)
        part_v[((size_t)es * BB + b0 + j) * DD + d] = acc[j];
}

// ---------------- K2: main single pass over hx (online softmax, 2-row groups, dbuf) ----------------
__global__ __launch_bounds__(256, 4) void k_main(const float* __restrict__ hx,
                                                 const float* __restrict__ mask,
                                                 const float* __restrict__ part_v,
                                                 const float* __restrict__ st,
                                                 const float* __restrict__ bias,
                                                 float* __restrict__ part) {
    const int chunk = blockIdx.x;
    const int b = blockIdx.y;
    const int tid = threadIdx.x;
    const int wave = tid >> 6;
    const int lane = tid & 63;

    // v fragment (lane l owns cols 256k+4l..+3), reduced over the 8 e-splits
    f32x4 vr[4];
#pragma unroll
    for (int k = 0; k < 4; ++k) vr[k] = (f32x4)(0.f);
#pragma unroll
    for (int es = 0; es < ESPL; ++es) {
        const float* pv = part_v + ((size_t)es * BB + b) * DD + 4 * lane;
#pragma unroll
        for (int k = 0; k < 4; ++k) vr[k] += ld4(pv + k * 256);
    }

    // cb = dot(bias, st[b]) computed redundantly per wave (L2-hot reads)
    float cb = 0.f;
    {
        const float* stb = st + b * DD + 4 * lane;
        const float* bb = bias + 4 * lane;
#pragma unroll
        for (int k = 0; k < 4; ++k) {
            f32x4 bv = ld4(bb + k * 256);
            f32x4 sv = ld4(stb + k * 256);
            cb += bv.x * sv.x + bv.y * sv.y + bv.z * sv.z + bv.w * sv.w;
        }
#pragma unroll
        for (int o = 32; o; o >>= 1) cb += __shfl_xor(cb, o, 64);
    }

    const int s0 = chunk * ROWS_PER_CHUNK + wave * ROWS_PER_WAVE;
    const float* hxb = hx + (size_t)b * SS * DD + 4 * lane;
    const float* mb = mask + (size_t)b * SS;

    float m = -INFINITY, l = 0.f;
    f32x4 u[4];
#pragma unroll
    for (int k = 0; k < 4; ++k) u[k] = (f32x4)(0.f);

    f32x4 hA[2][4], hB[2][4];

    auto loadrows = [&](f32x4 (&h)[2][4], int s) {
        const float* r0 = hxb + (size_t)s * DD;
#pragma unroll
        for (int k = 0; k < 4; ++k) {
            h[0][k] = ldnt4(r0 + k * 256);
            h[1][k] = ldnt4(r0 + DD + k * 256);
        }
    };

    auto compute = [&](const f32x4 (&h)[2][4], int s) {
        float d0 = 0.f, d1 = 0.f;
#pragma unroll
        for (int k = 0; k < 4; ++k) {
            d0 += h[0][k].x * vr[k].x + h[0][k].y * vr[k].y + h[0][k].z * vr[k].z + h[0][k].w * vr[k].w;
            d1 += h[1][k].x * vr[k].x + h[1][k].y * vr[k].y + h[1][k].z * vr[k].z + h[1][k].w * vr[k].w;
        }
        // select-mix reduce: 1 mix + 5 butterfly + 1 gather = 7 shfls for 2 rows
        const bool odd = (lane & 1);
        float a = odd ? d1 : d0;
        float t = odd ? d0 : d1;
        a += __shfl_xor(t, 1, 64);
        a += __shfl_xor(a, 2, 64);
        a += __shfl_xor(a, 4, 64);
        a += __shfl_xor(a, 8, 64);
        a += __shfl_xor(a, 16, 64);
        a += __shfl_xor(a, 32, 64);
        const float o = __shfl_xor(a, 1, 64);
        const float dd0 = odd ? o : a;
        const float dd1 = odd ? a : o;

        const float2 mk = *reinterpret_cast<const float2*>(mb + s);
        const float sc0 = (dd0 + cb) * (mk.x + (1.0f - mk.x) * 1e-18f);
        const float sc1 = (dd1 + cb) * (mk.y + (1.0f - mk.y) * 1e-18f);

        const float gm = fmaxf(sc0, sc1);
        if (gm > m) {                        // wave-uniform (post-reduce values)
            const float f = __expf(m - gm);  // 0 on first group (m = -inf)
            l *= f;
#pragma unroll
            for (int k = 0; k < 4; ++k) u[k] *= f;
            m = gm;
        }
        const float p0 = __expf(sc0 - m);
        const float p1 = __expf(sc1 - m);
        l += p0 + p1;
#pragma unroll
        for (int k = 0; k < 4; ++k) u[k] += p0 * h[0][k] + p1 * h[1][k];
    };

    // software pipeline over 8 groups of 2 rows, static A/B alternation
    loadrows(hA, s0);
#pragma unroll
    for (int g = 0; g < ROWS_PER_WAVE / 2 - 1; ++g) {
        if (g & 1) { loadrows(hA, s0 + 2 * (g + 1)); compute(hB, s0 + 2 * g); }
        else       { loadrows(hB, s0 + 2 * (g + 1)); compute(hA, s0 + 2 * g); }
    }
    compute(hB, s0 + ROWS_PER_WAVE - 2);   // last group (loaded at g=6 into hB)

    // combine 4 waves in LDS
    __shared__ float s_m[NWAVES], s_l[NWAVES];
    __shared__ float s_u[NWAVES][DD];   // 16 KB
    if (lane == 0) { s_m[wave] = m; s_l[wave] = l; }
#pragma unroll
    for (int k = 0; k < 4; ++k)
        *reinterpret_cast<f32x4*>(&s_u[wave][k * 256 + 4 * lane]) = u[k];
    __syncthreads();

    const float M = fmaxf(fmaxf(s_m[0], s_m[1]), fmaxf(s_m[2], s_m[3]));
    const float f0 = __expf(s_m[0] - M), f1 = __expf(s_m[1] - M);
    const float f2 = __expf(s_m[2] - M), f3 = __expf(s_m[3] - M);
    const float L = s_l[0] * f0 + s_l[1] * f1 + s_l[2] * f2 + s_l[3] * f3;

    float* pb = part + (size_t)(b * CHUNKS + chunk) * PSTRIDE;
    f32x4 a0 = ld4(&s_u[0][4 * tid]);
    f32x4 a1 = ld4(&s_u[1][4 * tid]);
    f32x4 a2 = ld4(&s_u[2][4 * tid]);
    f32x4 a3 = ld4(&s_u[3][4 * tid]);
    f32x4 acc = a0 * f0 + a1 * f1 + a2 * f2 + a3 * f3;
    *reinterpret_cast<f32x4*>(pb + 4 * tid) = acc;
    if (tid == 0) { pb[DD] = M; pb[DD + 1] = L; }
}

// ---------------- K3: combine chunks -> ubar[b,d] = u_total/L (128 one-wave blocks) ----------------
__global__ __launch_bounds__(64) void k_reduce(const float* __restrict__ part,
                                               float* __restrict__ ubar) {
    const int dc = blockIdx.x;           // 0..3 (256-col slice)
    const int b = blockIdx.y;            // 0..31
    const int lane = threadIdx.x;        // 0..63
    const float* pb = part + (size_t)b * CHUNKS * PSTRIDE;

    const float mi = (lane < CHUNKS) ? pb[lane * PSTRIDE + DD] : -INFINITY;
    float M = mi;
#pragma unroll
    for (int o = 32; o; o >>= 1) M = fmaxf(M, __shfl_xor(M, o, 64));
    const float li = (lane < CHUNKS) ? pb[lane * PSTRIDE + DD + 1] : 0.f;
    const float fi = (lane < CHUNKS) ? __expf(mi - M) : 0.f;
    float L = li * fi;
#pragma unroll
    for (int o = 32; o; o >>= 1) L += __shfl_xor(L, o, 64);
    const float invL = 1.f / L;

    const int col = dc * 256 + 4 * lane;
    f32x4 acc = (f32x4)(0.f);
#pragma unroll 8
    for (int i = 0; i < CHUNKS; ++i) {
        const float f = __shfl(fi, i, 64);
        acc += f * ld4(pb + (size_t)i * PSTRIDE + col);
    }
    acc *= invL;
    *reinterpret_cast<f32x4*>(ubar + (size_t)b * DD + col) = acc;
}

// ---------------- K4: ct[b,e] = sum_d ubar[b,d]*W[e,d] + bias[e] (coalesced W rows) ----------------
__global__ __launch_bounds__(256) void k_out(const float* __restrict__ ubar,
                                             const float* __restrict__ W,
                                             const float* __restrict__ bias,
                                             float* __restrict__ out) {
    const int echunk = blockIdx.x;       // 0..63 (16 e each)
    const int bg = blockIdx.y;           // 0..7  (4 b each)
    const int tid = threadIdx.x;
    const int wave = tid >> 6;
    const int lane = tid & 63;
    const int b0 = bg * 4;

    // ubar fragments for 4 batches, lane-pattern 256k+4l
    f32x4 ur[4][4];
#pragma unroll
    for (int j = 0; j < 4; ++j) {
        const float* ub = ubar + (size_t)(b0 + j) * DD + 4 * lane;
#pragma unroll
        for (int k = 0; k < 4; ++k) ur[j][k] = ld4(ub + k * 256);
    }

    for (int i = 0; i < 4; ++i) {
        const int e = echunk * 16 + wave * 4 + i;
        const float* wr = W + (size_t)e * DD + 4 * lane;
        f32x4 w4[4];
#pragma unroll
        for (int k = 0; k < 4; ++k) w4[k] = ld4(wr + k * 256);

        float d0 = 0.f, d1 = 0.f, d2 = 0.f, d3 = 0.f;
#pragma unroll
        for (int k = 0; k < 4; ++k) {
            d0 += w4[k].x * ur[0][k].x + w4[k].y * ur[0][k].y + w4[k].z * ur[0][k].z + w4[k].w * ur[0][k].w;
            d1 += w4[k].x * ur[1][k].x + w4[k].y * ur[1][k].y + w4[k].z * ur[1][k].z + w4[k].w * ur[1][k].w;
            d2 += w4[k].x * ur[2][k].x + w4[k].y * ur[2][k].y + w4[k].z * ur[2][k].z + w4[k].w * ur[2][k].w;
            d3 += w4[k].x * ur[3][k].x + w4[k].y * ur[3][k].y + w4[k].z * ur[3][k].z + w4[k].w * ur[3][k].w;
        }
#pragma unroll
        for (int o = 32; o; o >>= 1) {
            d0 += __shfl_xor(d0, o, 64);
            d1 += __shfl_xor(d1, o, 64);
            d2 += __shfl_xor(d2, o, 64);
            d3 += __shfl_xor(d3, o, 64);
        }
        if (lane == 0) {
            const float be = bias[e];
            out[(size_t)(b0 + 0) * DD + e] = d0 + be;
            out[(size_t)(b0 + 1) * DD + e] = d1 + be;
            out[(size_t)(b0 + 2) * DD + e] = d2 + be;
            out[(size_t)(b0 + 3) * DD + e] = d3 + be;
        }
    }
}

extern "C" void kernel_launch(void* const* d_in, const int* in_sizes, int n_in,
                              void* d_out, int out_size, void* d_ws, size_t ws_size,
                              hipStream_t stream) {
    const float* st   = (const float*)d_in[0];   // [B,D]
    const float* hx   = (const float*)d_in[1];   // [B,S,D]
    const float* msk  = (const float*)d_in[2];   // [B,S]
    const float* W    = (const float*)d_in[3];   // [D,D]
    const float* bias = (const float*)d_in[4];   // [D]
    float* out = (float*)d_out;                  // [B,D]

    float* ws = (float*)d_ws;
    float* part_v = ws;                                   // ESPL*B*D = 256K floats
    float* part   = part_v + (size_t)ESPL * BB * DD;      // B*CHUNKS*PSTRIDE
    float* ubar   = part + (size_t)BB * CHUNKS * PSTRIDE; // B*D

    k_v<<<dim3(4, ESPL, VBG), 256, 0, stream>>>(st, W, part_v);
    k_main<<<dim3(CHUNKS, BB), 256, 0, stream>>>(hx, msk, part_v, st, bias, part);
    k_reduce<<<dim3(DSPL, BB), 64, 0, stream>>>(part, ubar);
    k_out<<<dim3(64, 8), 256, 0, stream>>>(ubar, W, bias, out);
}

// Round 7
// 65.513 us; speedup vs baseline: 1.1955x; 1.0658x over previous
//
#include <hip/hip_runtime.h>
#include <math.h>

#define BB 32
#define SS 2048
#define DD 1024
#define CHUNKS 32                        // chunks per batch (k_main grid.x)
#define ROWS_PER_CHUNK (SS / CHUNKS)     // 64
#define NWAVES 4
#define ROWS_PER_WAVE (ROWS_PER_CHUNK / NWAVES)  // 16
#define PSTRIDE (DD + 4)                 // partial stride (16B aligned)

// k_v split
#define ESPL 8
#define EPB (DD / ESPL)                  // 128 e per block
#define VBG 8                            // b-group blocks
#define VBPG (BB / VBG)                  // 4 b per block

// k_reduce split
#define DSPL 4                           // 256 cols per block

typedef float f32x4 __attribute__((ext_vector_type(4)));

__device__ __forceinline__ f32x4 ld4(const float* p) {
    return *reinterpret_cast<const f32x4*>(p);
}

// ---------------- K1: part_v[es][b][d] = sum_{e in es-range} st[b,e]*W[e,d] ----------------
// 16 independent W loads in flight per group (latency-bound fix).
__global__ __launch_bounds__(256) void k_v(const float* __restrict__ st,
                                           const float* __restrict__ W,
                                           float* __restrict__ part_v) {
    const int dchunk = blockIdx.x;       // 0..3
    const int es = blockIdx.y;           // 0..7
    const int bg = blockIdx.z;           // 0..7
    const int tid = threadIdx.x;
    const int d = dchunk * 256 + tid;
    const int e0 = es * EPB;
    const int b0 = bg * VBPG;

    __shared__ float st_s[VBPG][EPB];    // 2 KB
    for (int i = tid; i < VBPG * EPB; i += 256)
        st_s[i >> 7][i & 127] = st[(b0 + (i >> 7)) * DD + e0 + (i & 127)];
    __syncthreads();

    float acc[VBPG];
#pragma unroll
    for (int j = 0; j < VBPG; ++j) acc[j] = 0.f;

    const float* Wd = W + d;
    for (int e = 0; e < EPB; e += 16) {
        float w[16];
#pragma unroll
        for (int q = 0; q < 16; ++q)
            w[q] = Wd[(size_t)(e0 + e + q) * DD];
#pragma unroll
        for (int q = 0; q < 16; ++q)
#pragma unroll
            for (int j = 0; j < VBPG; ++j) acc[j] += st_s[j][e + q] * w[q];
    }
#pragma unroll
    for (int j = 0; j < VBPG; ++j)
        part_v[((size_t)es * BB + b0 + j) * DD + d] = acc[j];
}

// ---------------- K2: main single pass over hx (online softmax, 2-row groups, dbuf) ----------------
__global__ __launch_bounds__(256, 4) void k_main(const float* __restrict__ hx,
                                                 const float* __restrict__ mask,
                                                 const float* __restrict__ part_v,
                                                 const float* __restrict__ st,
                                                 const float* __restrict__ bias,
                                                 float* __restrict__ part) {
    const int chunk = blockIdx.x;
    const int b = blockIdx.y;
    const int tid = threadIdx.x;
    const int wave = tid >> 6;
    const int lane = tid & 63;

    const int s0 = chunk * ROWS_PER_CHUNK + wave * ROWS_PER_WAVE;
    const float* hxb = hx + (size_t)b * SS * DD + 4 * lane;
    const float* mb = mask + (size_t)b * SS;

    f32x4 hA[2][4], hB[2][4];
    auto loadrows = [&](f32x4 (&h)[2][4], int s) {
        const float* r0 = hxb + (size_t)s * DD;
#pragma unroll
        for (int k = 0; k < 4; ++k) {
            h[0][k] = ld4(r0 + k * 256);
            h[1][k] = ld4(r0 + DD + k * 256);
        }
    };

    // start the hx stream IMMEDIATELY (prologue hides under these loads)
    loadrows(hA, s0);
    loadrows(hB, s0 + 2);

    // v fragment (lane l owns cols 256k+4l..+3), reduced over the 8 e-splits
    f32x4 vr[4];
#pragma unroll
    for (int k = 0; k < 4; ++k) vr[k] = (f32x4)(0.f);
#pragma unroll
    for (int es = 0; es < ESPL; ++es) {
        const float* pv = part_v + ((size_t)es * BB + b) * DD + 4 * lane;
#pragma unroll
        for (int k = 0; k < 4; ++k) vr[k] += ld4(pv + k * 256);
    }

    // cb = dot(bias, st[b]) computed redundantly per wave (L2-hot reads)
    float cb = 0.f;
    {
        const float* stb = st + b * DD + 4 * lane;
        const float* bb = bias + 4 * lane;
#pragma unroll
        for (int k = 0; k < 4; ++k) {
            f32x4 bv = ld4(bb + k * 256);
            f32x4 sv = ld4(stb + k * 256);
            cb += bv.x * sv.x + bv.y * sv.y + bv.z * sv.z + bv.w * sv.w;
        }
#pragma unroll
        for (int o = 32; o; o >>= 1) cb += __shfl_xor(cb, o, 64);
    }

    float m = -INFINITY, l = 0.f;
    f32x4 u[4];
#pragma unroll
    for (int k = 0; k < 4; ++k) u[k] = (f32x4)(0.f);

    auto compute = [&](const f32x4 (&h)[2][4], int s) {
        float d0 = 0.f, d1 = 0.f;
#pragma unroll
        for (int k = 0; k < 4; ++k) {
            d0 += h[0][k].x * vr[k].x + h[0][k].y * vr[k].y + h[0][k].z * vr[k].z + h[0][k].w * vr[k].w;
            d1 += h[1][k].x * vr[k].x + h[1][k].y * vr[k].y + h[1][k].z * vr[k].z + h[1][k].w * vr[k].w;
        }
        // select-mix reduce: 1 mix + 5 butterfly + 1 gather = 7 shfls for 2 rows
        const bool odd = (lane & 1);
        float a = odd ? d1 : d0;
        float t = odd ? d0 : d1;
        a += __shfl_xor(t, 1, 64);
        a += __shfl_xor(a, 2, 64);
        a += __shfl_xor(a, 4, 64);
        a += __shfl_xor(a, 8, 64);
        a += __shfl_xor(a, 16, 64);
        a += __shfl_xor(a, 32, 64);
        const float o = __shfl_xor(a, 1, 64);
        const float dd0 = odd ? o : a;
        const float dd1 = odd ? a : o;

        const float2 mk = *reinterpret_cast<const float2*>(mb + s);
        const float sc0 = (dd0 + cb) * (mk.x + (1.0f - mk.x) * 1e-18f);
        const float sc1 = (dd1 + cb) * (mk.y + (1.0f - mk.y) * 1e-18f);

        const float gm = fmaxf(sc0, sc1);
        if (gm > m) {                        // wave-uniform (post-reduce values)
            const float f = __expf(m - gm);  // 0 on first group (m = -inf)
            l *= f;
#pragma unroll
            for (int k = 0; k < 4; ++k) u[k] *= f;
            m = gm;
        }
        const float p0 = __expf(sc0 - m);
        const float p1 = __expf(sc1 - m);
        l += p0 + p1;
#pragma unroll
        for (int k = 0; k < 4; ++k) u[k] += p0 * h[0][k] + p1 * h[1][k];
    };

    // 2-deep software pipeline over 8 groups of 2 rows, static A/B alternation
#pragma unroll
    for (int g = 0; g < ROWS_PER_WAVE / 2 - 2; ++g) {
        if (g & 1) { compute(hB, s0 + 2 * g); loadrows(hB, s0 + 2 * (g + 2)); }
        else       { compute(hA, s0 + 2 * g); loadrows(hA, s0 + 2 * (g + 2)); }
    }
    compute(hA, s0 + ROWS_PER_WAVE - 4);
    compute(hB, s0 + ROWS_PER_WAVE - 2);

    // combine 4 waves in LDS
    __shared__ float s_m[NWAVES], s_l[NWAVES];
    __shared__ float s_u[NWAVES][DD];   // 16 KB
    if (lane == 0) { s_m[wave] = m; s_l[wave] = l; }
#pragma unroll
    for (int k = 0; k < 4; ++k)
        *reinterpret_cast<f32x4*>(&s_u[wave][k * 256 + 4 * lane]) = u[k];
    __syncthreads();

    const float M = fmaxf(fmaxf(s_m[0], s_m[1]), fmaxf(s_m[2], s_m[3]));
    const float f0 = __expf(s_m[0] - M), f1 = __expf(s_m[1] - M);
    const float f2 = __expf(s_m[2] - M), f3 = __expf(s_m[3] - M);
    const float L = s_l[0] * f0 + s_l[1] * f1 + s_l[2] * f2 + s_l[3] * f3;

    float* pb = part + (size_t)(b * CHUNKS + chunk) * PSTRIDE;
    f32x4 a0 = ld4(&s_u[0][4 * tid]);
    f32x4 a1 = ld4(&s_u[1][4 * tid]);
    f32x4 a2 = ld4(&s_u[2][4 * tid]);
    f32x4 a3 = ld4(&s_u[3][4 * tid]);
    f32x4 acc = a0 * f0 + a1 * f1 + a2 * f2 + a3 * f3;
    *reinterpret_cast<f32x4*>(pb + 4 * tid) = acc;
    if (tid == 0) { pb[DD] = M; pb[DD + 1] = L; }
}

// ---------------- K3: combine chunks -> ubar[b,d] = u_total/L (128 one-wave blocks) ----------------
__global__ __launch_bounds__(64) void k_reduce(const float* __restrict__ part,
                                               float* __restrict__ ubar) {
    const int dc = blockIdx.x;           // 0..3 (256-col slice)
    const int b = blockIdx.y;            // 0..31
    const int lane = threadIdx.x;        // 0..63
    const float* pb = part + (size_t)b * CHUNKS * PSTRIDE;

    const float mi = (lane < CHUNKS) ? pb[lane * PSTRIDE + DD] : -INFINITY;
    float M = mi;
#pragma unroll
    for (int o = 32; o; o >>= 1) M = fmaxf(M, __shfl_xor(M, o, 64));
    const float li = (lane < CHUNKS) ? pb[lane * PSTRIDE + DD + 1] : 0.f;
    const float fi = (lane < CHUNKS) ? __expf(mi - M) : 0.f;
    float L = li * fi;
#pragma unroll
    for (int o = 32; o; o >>= 1) L += __shfl_xor(L, o, 64);
    const float invL = 1.f / L;

    const int col = dc * 256 + 4 * lane;
    f32x4 acc = (f32x4)(0.f);
#pragma unroll 8
    for (int i = 0; i < CHUNKS; ++i) {
        const float f = __shfl(fi, i, 64);
        acc += f * ld4(pb + (size_t)i * PSTRIDE + col);
    }
    acc *= invL;
    *reinterpret_cast<f32x4*>(ubar + (size_t)b * DD + col) = acc;
}

// ---------------- K4: ct[b,e] = sum_d ubar[b,d]*W[e,d] + bias[e] (coalesced W rows) ----------------
__global__ __launch_bounds__(256) void k_out(const float* __restrict__ ubar,
                                             const float* __restrict__ W,
                                             const float* __restrict__ bias,
                                             float* __restrict__ out) {
    const int echunk = blockIdx.x;       // 0..63 (16 e each)
    const int bg = blockIdx.y;           // 0..7  (4 b each)
    const int tid = threadIdx.x;
    const int wave = tid >> 6;
    const int lane = tid & 63;
    const int b0 = bg * 4;

    // ubar fragments for 4 batches, lane-pattern 256k+4l
    f32x4 ur[4][4];
#pragma unroll
    for (int j = 0; j < 4; ++j) {
        const float* ub = ubar + (size_t)(b0 + j) * DD + 4 * lane;
#pragma unroll
        for (int k = 0; k < 4; ++k) ur[j][k] = ld4(ub + k * 256);
    }

    for (int i = 0; i < 4; ++i) {
        const int e = echunk * 16 + wave * 4 + i;
        const float* wr = W + (size_t)e * DD + 4 * lane;
        f32x4 w4[4];
#pragma unroll
        for (int k = 0; k < 4; ++k) w4[k] = ld4(wr + k * 256);

        float d0 = 0.f, d1 = 0.f, d2 = 0.f, d3 = 0.f;
#pragma unroll
        for (int k = 0; k < 4; ++k) {
            d0 += w4[k].x * ur[0][k].x + w4[k].y * ur[0][k].y + w4[k].z * ur[0][k].z + w4[k].w * ur[0][k].w;
            d1 += w4[k].x * ur[1][k].x + w4[k].y * ur[1][k].y + w4[k].z * ur[1][k].z + w4[k].w * ur[1][k].w;
            d2 += w4[k].x * ur[2][k].x + w4[k].y * ur[2][k].y + w4[k].z * ur[2][k].z + w4[k].w * ur[2][k].w;
            d3 += w4[k].x * ur[3][k].x + w4[k].y * ur[3][k].y + w4[k].z * ur[3][k].z + w4[k].w * ur[3][k].w;
        }
#pragma unroll
        for (int o = 32; o; o >>= 1) {
            d0 += __shfl_xor(d0, o, 64);
            d1 += __shfl_xor(d1, o, 64);
            d2 += __shfl_xor(d2, o, 64);
            d3 += __shfl_xor(d3, o, 64);
        }
        if (lane == 0) {
            const float be = bias[e];
            out[(size_t)(b0 + 0) * DD + e] = d0 + be;
            out[(size_t)(b0 + 1) * DD + e] = d1 + be;
            out[(size_t)(b0 + 2) * DD + e] = d2 + be;
            out[(size_t)(b0 + 3) * DD + e] = d3 + be;
        }
    }
}

extern "C" void kernel_launch(void* const* d_in, const int* in_sizes, int n_in,
                              void* d_out, int out_size, void* d_ws, size_t ws_size,
                              hipStream_t stream) {
    const float* st   = (const float*)d_in[0];   // [B,D]
    const float* hx   = (const float*)d_in[1];   // [B,S,D]
    const float* msk  = (const float*)d_in[2];   // [B,S]
    const float* W    = (const float*)d_in[3];   // [D,D]
    const float* bias = (const float*)d_in[4];   // [D]
    float* out = (float*)d_out;                  // [B,D]

    float* ws = (float*)d_ws;
    float* part_v = ws;                                   // ESPL*B*D = 256K floats
    float* part   = part_v + (size_t)ESPL * BB * DD;      // B*CHUNKS*PSTRIDE
    float* ubar   = part + (size_t)BB * CHUNKS * PSTRIDE; // B*D

    k_v<<<dim3(4, ESPL, VBG), 256, 0, stream>>>(st, W, part_v);
    k_main<<<dim3(CHUNKS, BB), 256, 0, stream>>>(hx, msk, part_v, st, bias, part);
    k_reduce<<<dim3(DSPL, BB), 64, 0, stream>>>(part, ubar);
    k_out<<<dim3(64, 8), 256, 0, stream>>>(ubar, W, bias, out);
}